// Round 2
// baseline (273.013 us; speedup 1.0000x reference)
//
#include <hip/hip_runtime.h>
#include <cfloat>

// VectorQuantizer: N=32768 rows, K=8192 codes, D=256, fp32.
// R2/R3 (absmax 0): reference = numpy fp32; d_k = fl32(fl32(x2+wn_k)-fl32(2*m_k)),
// m_k = single fp32 FMA chain d-ascending; first-occurrence argmin. Exact top-8
// rescore of approximate-scorer candidates reproduces it bit-for-bit.
// R6: 2 blocks/CU residency, in-kernel A fp8 conversion, top-2/slot keys.
// R7: vq_score stall removal (counters: MfmaUtil 22.5% = 29us MFMA floor /
// 125us wall; 63% of each kt stalled on syncthreads vmcnt(0) drain + MFMA
// chain + selection on critical path):
//   - tile split into two 16KB K-halves, 4 LDS buffers (same 64KB), prefetch
//     depth 3 halves; barriers are "s_waitcnt vmcnt(8); s_barrier" (counted,
//     never drain to 0 in-loop).  K-major-per-col LDS layout, source-side XOR
//     pre-swizzle (granule g stored at slot g^(col&7)); register data mapping
//     identical to the R6-verified kernel.
//   - selection DEFERRED one kt (two acc sets): selection VALU of kt-1 runs in
//     the MFMA shadow of kt. Same values, same comparisons, same results.
//   - s1 update via v_med3_u32 (== min(max(key,s0),s1) given s0<=s1, bit-
//     identical): 3 VALU/key instead of 4.
//   - s_setprio(1) around MFMA clusters.
// R8: R7 run died to an infra flake ("container failed twice", no counters).
// Kernel re-audited for hang/fault paths (barrier uniformity, vmcnt ledger,
// global/LDS bounds all clean) -> resubmitted unchanged.
// prep_w / rescore untouched (bit-exact verified).

#define DDIM 256

typedef int   i32x8  __attribute__((ext_vector_type(8)));
typedef float f32x16 __attribute__((ext_vector_type(16)));

// ---------- W prep: numpy-exact ||w||^2 + negated scaled fp8 ----------
__global__ __launch_bounds__(256) void vq_prep_w(
    const float* __restrict__ w, float* __restrict__ wn,
    unsigned char* __restrict__ wb8) {
    __shared__ float rows[32 * 260];
    const int tid = threadIdx.x;
    const int r0 = blockIdx.x * 32;

    for (int idx = tid; idx < 32 * 64; idx += 256) {
        int r = idx >> 6, c4 = idx & 63;
        *(float4*)&rows[r * 260 + c4 * 4] =
            *(const float4*)(w + (size_t)(r0 + r) * DDIM + c4 * 4);
    }
    __syncthreads();
    {
        // numpy pairwise_sum(fl(a*a),256): two 128-halves, each 8 stride-8
        // chains, ((r0+r1)+(r2+r3))+((r4+r5)+(r6+r7)); shfl-xor == nesting.
        const int row = (tid >> 6) * 8 + ((tid & 63) >> 3), j = tid & 7;
        const float* a = &rows[row * 260];
        float half[2];
#pragma unroll
        for (int h = 0; h < 2; ++h) {
            const float* b = a + h * 128 + j;
            float r = __fmul_rn(b[0], b[0]);
#pragma unroll
            for (int t = 1; t < 16; ++t)
                r = __fadd_rn(r, __fmul_rn(b[8 * t], b[8 * t]));
            float p = __fadd_rn(r, __shfl_xor(r, 1, 64));
            p = __fadd_rn(p, __shfl_xor(p, 2, 64));
            p = __fadd_rn(p, __shfl_xor(p, 4, 64));
            half[h] = p;
        }
        if (j == 0) wn[r0 + row] = __fadd_rn(half[0], half[1]);
    }
    // fp8 e4m3 emission, scaled by -2^13 (pow2 cancels in argmin; negation
    // folds the "-2m" sign so acc = C - m_s with C=128 init)
    for (int idx = tid; idx < 32 * 16; idx += 256) {
        int r = idx >> 4, s = idx & 15;
        const float* p = &rows[r * 260 + s * 16];
        unsigned q[4];
#pragma unroll
        for (int m = 0; m < 4; ++m) {
            unsigned v = (unsigned)__builtin_amdgcn_cvt_pk_fp8_f32(
                p[m * 4 + 0] * -8192.f, p[m * 4 + 1] * -8192.f, 0, false);
            v = (unsigned)__builtin_amdgcn_cvt_pk_fp8_f32(
                p[m * 4 + 2] * -8192.f, p[m * 4 + 3] * -8192.f, (int)v, true);
            q[m] = v;
        }
        *(uint4*)(wb8 + (size_t)(r0 + r) * DDIM + s * 16) =
            make_uint4(q[0], q[1], q[2], q[3]);
    }
}

// ---------- MX-fp8 scorer: 64 rows x 8192 cols per block, 2 blocks/CU ----------
// 256 thr = 4 waves (wave = 32-col group); wave tile 64r x 32c = 2 MFMA
// 32x32x64 tiles. A resident in VGPRs. W staged as 16KB K-half tiles into 4
// LDS buffers; counted-vmcnt pipeline, prefetch depth 3 halves.
// C/D (32x32): col=lane&31, row=(reg&3)+8*(reg>>2)+4*(lane>>5)  [m74/m101].
//
// Pipeline invariants (half index h = 2*kt + hh, buffer = h&3):
//   program order per half-step: WBAR -> stage(h+3) -> compute(h)
//   - at WBAR of half h, outstanding = halves {h, h+1, h+2} = 12 loads/wave;
//     vmcnt(8) completes the oldest 4 = half h.  Tail: h=126 -> 4, h=127 -> 0.
//   - stage(h+3) overwrites buffer (h-1)&3; the barrier of half h guarantees
//     every wave finished compute(h-1) (its ds_reads retired before its MFMAs).
//   - no other VMEM ops exist inside the loop, so vmcnt counts only staging.

#define WBARi(n) asm volatile("s_waitcnt vmcnt(" #n ")\n\ts_barrier" ::: "memory")

#define INIT128(C) { _Pragma("unroll") for (int r_ = 0; r_ < 16; ++r_) (C)[r_] = 128.0f; }

// top-2 tracking: s0 <= s1 invariant; med3(key,s0,s1) == min(max(key,s0),s1)
// given the invariant -> bit-identical to R6's {max,min,min}, one op fewer.
#define SEL16(P, rt, pkt) { \
    const unsigned colv_ = (unsigned)((pkt) * 128 + bcol); \
    _Pragma("unroll") for (int r_ = 0; r_ < 16; ++r_) { \
        unsigned key_ = (__float_as_uint((P)[r_]) & 0xFFFFE000u) | colv_; \
        unsigned a0_ = s0[rt][r_]; \
        unsigned m1_; \
        asm("v_med3_u32 %0, %1, %2, %3" \
            : "=v"(m1_) : "v"(key_), "v"(a0_), "v"(s1[rt][r_])); \
        s1[rt][r_] = m1_; \
        s0[rt][r_] = key_ < a0_ ? key_ : a0_; \
    } }

// one 16KB K-half: 2 ks-steps x 2 row-tiles = 4 MFMAs
#define KS2(bufi, KA, KB, C0, C1) do { \
    union { uint4 q[2]; i32x8 v; } b_; \
    b_.q[0] = *(const uint4*)(wsb + (bufi) * 16384 + rb[0]); \
    b_.q[1] = *(const uint4*)(wsb + (bufi) * 16384 + rb[1]); \
    C0 = __builtin_amdgcn_mfma_scale_f32_32x32x64_f8f6f4( \
        af[0][KA], b_.v, C0, 0, 0, 0, 0x7F7F7F7F, 0, 0x7F7F7F7F); \
    C1 = __builtin_amdgcn_mfma_scale_f32_32x32x64_f8f6f4( \
        af[1][KA], b_.v, C1, 0, 0, 0, 0x7F7F7F7F, 0, 0x7F7F7F7F); \
    b_.q[0] = *(const uint4*)(wsb + (bufi) * 16384 + rb[2]); \
    b_.q[1] = *(const uint4*)(wsb + (bufi) * 16384 + rb[3]); \
    C0 = __builtin_amdgcn_mfma_scale_f32_32x32x64_f8f6f4( \
        af[0][KB], b_.v, C0, 0, 0, 0, 0x7F7F7F7F, 0, 0x7F7F7F7F); \
    C1 = __builtin_amdgcn_mfma_scale_f32_32x32x64_f8f6f4( \
        af[1][KB], b_.v, C1, 0, 0, 0, 0x7F7F7F7F, 0, 0x7F7F7F7F); \
  } while (0)

__global__ __launch_bounds__(256, 2) void vq_score(
    const float* __restrict__ x, const unsigned char* __restrict__ wb8,
    unsigned* __restrict__ cand) {
    __shared__ __align__(16) unsigned char Ws[4][16384];
    const int tid = threadIdx.x;
    const int wave = tid >> 6, lane = tid & 63;
    const int h = lane >> 5, c32 = lane & 31;
    const int rowBase = blockIdx.x * 64;
    const unsigned char* wsb = (const unsigned char*)&Ws[0][0];

    // A fragments: 64 rows x 256 k fp8, converted from fp32 global (one-time)
    i32x8 af[2][4];
#pragma unroll
    for (int rt = 0; rt < 2; ++rt) {
        const float* xr = x + (size_t)(rowBase + rt * 32 + c32) * DDIM;
#pragma unroll
        for (int ks = 0; ks < 4; ++ks) {
            const float4* p = (const float4*)(xr + ks * 64 + h * 32);
            union { int d[8]; i32x8 v; } u;
#pragma unroll
            for (int m = 0; m < 8; ++m) {
                float4 f = p[m];
                unsigned v = (unsigned)__builtin_amdgcn_cvt_pk_fp8_f32(
                    f.x, f.y, 0, false);
                v = (unsigned)__builtin_amdgcn_cvt_pk_fp8_f32(
                    f.z, f.w, (int)v, true);
                u.d[m] = (int)v;
            }
            af[rt][ks] = u.v;
        }
    }
    // clean vmcnt baseline for the counted pipeline
    asm volatile("s_waitcnt vmcnt(0)" ::: "memory");

    // staging: half-tile = 128 cols x 128B (one K-half) = 16KB = 4 instr/wave.
    // instr i covers cols slot*8..+7 (slot = wave*4+i); 8 lanes/col read the
    // col's contiguous 128B with granules permuted by ^c (source pre-swizzle),
    // LDS dest linear: granule g of col lands at byte col*128 + (g^(col&7))*16.
    const unsigned laneTerm =
        (unsigned)((lane >> 3) * 256 + (((lane & 7) ^ (lane >> 3)) * 16));
    auto stage = [&](int hh) {
        const unsigned char* g = wb8 + (size_t)(hh >> 1) * 32768 +
                                 (hh & 1) * 128 + wave * 8192 + laneTerm;
        const int bb = (hh & 3) * 16384 + wave * 4096;
#pragma unroll
        for (int i = 0; i < 4; ++i)
            __builtin_amdgcn_global_load_lds(
                (const __attribute__((address_space(1))) unsigned int*)(g + i * 2048),
                (__attribute__((address_space(3))) unsigned int*)(
                    &Ws[0][0] + bb + i * 1024),
                16, 0, 0);
    };

    // B-fragment read offsets: granule g3 of col bcol sits at
    // bcol*128 + (g3 ^ (bcol&7))*16 inside a half-buffer.
    const int bcol = wave * 32 + c32, cs = bcol & 7;
    unsigned rb[4];
    {
        const int e0 = h * 2;
        rb[0] = (unsigned)(bcol * 128 + ((e0 ^ cs) * 16));
        rb[1] = (unsigned)(bcol * 128 + (((e0 + 1) ^ cs) * 16));
        rb[2] = (unsigned)(bcol * 128 + (((e0 + 4) ^ cs) * 16));
        rb[3] = (unsigned)(bcol * 128 + (((e0 + 5) ^ cs) * 16));
    }

    unsigned s0[2][16], s1[2][16];
#pragma unroll
    for (int a = 0; a < 2; ++a)
#pragma unroll
        for (int r = 0; r < 16; ++r) { s0[a][r] = 0xFFFFFFFFu; s1[a][r] = 0xFFFFFFFFu; }

    f32x16 cA0, cA1, cB0, cB1;

    stage(0); stage(1); stage(2);

    // kt = 0 -> cB (nothing to select yet); bufs 0,1
    INIT128(cB0); INIT128(cB1);
    WBARi(8); stage(3);
    __builtin_amdgcn_s_setprio(1); KS2(0, 0, 1, cB0, cB1); __builtin_amdgcn_s_setprio(0);
    WBARi(8); stage(4);
    __builtin_amdgcn_s_setprio(1); KS2(1, 2, 3, cB0, cB1); __builtin_amdgcn_s_setprio(0);

    for (int kt = 1; kt < 63; kt += 2) {
        // kt (odd): cur = cA (bufs 2,3); select prev cB (pkt = kt-1)
        INIT128(cA0); INIT128(cA1);
        WBARi(8); stage(2 * kt + 3);
        __builtin_amdgcn_s_setprio(1); KS2(2, 0, 1, cA0, cA1); __builtin_amdgcn_s_setprio(0);
        SEL16(cB0, 0, kt - 1);
        WBARi(8); stage(2 * kt + 4);
        __builtin_amdgcn_s_setprio(1); KS2(3, 2, 3, cA0, cA1); __builtin_amdgcn_s_setprio(0);
        SEL16(cB1, 1, kt - 1);
        // kt+1 (even): cur = cB (bufs 0,1); select prev cA (pkt = kt)
        INIT128(cB0); INIT128(cB1);
        WBARi(8); stage(2 * kt + 5);
        __builtin_amdgcn_s_setprio(1); KS2(0, 0, 1, cB0, cB1); __builtin_amdgcn_s_setprio(0);
        SEL16(cA0, 0, kt);
        WBARi(8); if (kt < 61) stage(2 * kt + 6);
        __builtin_amdgcn_s_setprio(1); KS2(1, 2, 3, cB0, cB1); __builtin_amdgcn_s_setprio(0);
        SEL16(cA1, 1, kt);
    }

    // kt = 63: cur = cA (bufs 2,3); select cB (pkt = 62); tail waits 4 -> 0
    INIT128(cA0); INIT128(cA1);
    WBARi(4);
    __builtin_amdgcn_s_setprio(1); KS2(2, 0, 1, cA0, cA1); __builtin_amdgcn_s_setprio(0);
    SEL16(cB0, 0, 62);
    WBARi(0);
    __builtin_amdgcn_s_setprio(1); KS2(3, 2, 3, cA0, cA1); __builtin_amdgcn_s_setprio(0);
    SEL16(cB1, 1, 62);
    SEL16(cA0, 0, 63);
    SEL16(cA1, 1, 63);

    // merge: 64 rows x 256 keys = 64 KB (reuse Ws)
    __syncthreads();
    unsigned* ms = (unsigned*)Ws;
#pragma unroll
    for (int rt = 0; rt < 2; ++rt)
#pragma unroll
        for (int r = 0; r < 16; ++r) {
            int rloc = rt * 32 + (r & 3) + 8 * (r >> 2) + 4 * h;
            *(uint2*)&ms[rloc * 256 + bcol * 2] = make_uint2(s0[rt][r], s1[rt][r]);
        }
    __syncthreads();
    if (tid < 64) {
        const uint4* rowk = (const uint4*)(ms + tid * 256);
        unsigned best[8];
#pragma unroll
        for (int i = 0; i < 8; ++i) best[i] = 0xFFFFFFFFu;
        for (int i = 0; i < 64; ++i) {
            uint4 qv = rowk[(i + tid) & 63];   // rotated: bank spread
            unsigned kk[4] = {qv.x, qv.y, qv.z, qv.w};
#pragma unroll
            for (int e = 0; e < 4; ++e) {
                unsigned key = kk[e];
                if (key < best[7]) {
                    best[7] = key;
#pragma unroll
                    for (int j = 7; j > 0; --j)
                        if (best[j] < best[j - 1]) {
                            unsigned t = best[j]; best[j] = best[j - 1]; best[j - 1] = t;
                        }
                }
            }
        }
        unsigned* out = cand + (size_t)(rowBase + tid) * 8;
#pragma unroll
        for (int i = 0; i < 8; ++i) out[i] = best[i];
    }
}

// ---------- exact rescore (fp32 chain, R3-verified) + inline numpy x2 ----------
__global__ __launch_bounds__(256) void vq_rescore_write(
    const float* __restrict__ x, const float* __restrict__ w,
    const float* __restrict__ wn, const unsigned* __restrict__ cand,
    float* __restrict__ outq, float* __restrict__ outi) {
    __shared__ int winners[32];
    const int tid = threadIdx.x;
    const int lr = tid >> 3, cc = tid & 7;
    const int row = blockIdx.x * 32 + lr;

    int k = (int)(cand[(size_t)row * 8 + cc] & 0x1FFFu);
    const float* xr = x + (size_t)row * DDIM;
    const float* wr = w + (size_t)k * DDIM;
    // dot: single fp32 fmaf chain d-ascending (BLAS-exact, R2/R3-verified)
    // x2: numpy pairwise (two halves, 8 stride-8 chains, exact nesting)
    float dot = 0.f;
    float half[2];
#pragma unroll
    for (int hh = 0; hh < 2; ++hh) {
        float r[8];
#pragma unroll
        for (int t = 0; t < 16; ++t) {
            const int d = hh * 128 + t * 8;
            float4 xa = *(const float4*)(xr + d);
            float4 xb = *(const float4*)(xr + d + 4);
            float4 wa = *(const float4*)(wr + d);
            float4 wb = *(const float4*)(wr + d + 4);
            dot = __fmaf_rn(xa.x, wa.x, dot); dot = __fmaf_rn(xa.y, wa.y, dot);
            dot = __fmaf_rn(xa.z, wa.z, dot); dot = __fmaf_rn(xa.w, wa.w, dot);
            dot = __fmaf_rn(xb.x, wb.x, dot); dot = __fmaf_rn(xb.y, wb.y, dot);
            dot = __fmaf_rn(xb.z, wb.z, dot); dot = __fmaf_rn(xb.w, wb.w, dot);
            if (t == 0) {
                r[0] = __fmul_rn(xa.x, xa.x); r[1] = __fmul_rn(xa.y, xa.y);
                r[2] = __fmul_rn(xa.z, xa.z); r[3] = __fmul_rn(xa.w, xa.w);
                r[4] = __fmul_rn(xb.x, xb.x); r[5] = __fmul_rn(xb.y, xb.y);
                r[6] = __fmul_rn(xb.z, xb.z); r[7] = __fmul_rn(xb.w, xb.w);
            } else {
                r[0] = __fadd_rn(r[0], __fmul_rn(xa.x, xa.x));
                r[1] = __fadd_rn(r[1], __fmul_rn(xa.y, xa.y));
                r[2] = __fadd_rn(r[2], __fmul_rn(xa.z, xa.z));
                r[3] = __fadd_rn(r[3], __fmul_rn(xa.w, xa.w));
                r[4] = __fadd_rn(r[4], __fmul_rn(xb.x, xb.x));
                r[5] = __fadd_rn(r[5], __fmul_rn(xb.y, xb.y));
                r[6] = __fadd_rn(r[6], __fmul_rn(xb.w == xb.w ? xb.z : xb.z, xb.z));
                r[7] = __fadd_rn(r[7], __fmul_rn(xb.w, xb.w));
            }
        }
        half[hh] = __fadd_rn(__fadd_rn(__fadd_rn(r[0], r[1]), __fadd_rn(r[2], r[3])),
                             __fadd_rn(__fadd_rn(r[4], r[5]), __fadd_rn(r[6], r[7])));
    }
    float x2v = __fadd_rn(half[0], half[1]);
    float dv = __fsub_rn(__fadd_rn(x2v, wn[k]), __fmul_rn(2.0f, dot));
    // lexicographic (dv,k) min across 8 candidate lanes (first-occurrence)
#pragma unroll
    for (int m = 1; m < 8; m <<= 1) {
        float od = __shfl_xor(dv, m, 64);
        int   ok = __shfl_xor(k,  m, 64);
        if (od < dv || (od == dv && ok < k)) { dv = od; k = ok; }
    }
    if (cc == 0) winners[lr] = k;
    __syncthreads();
    if (tid < 32) outi[blockIdx.x * 32 + tid] = (float)winners[tid];
    for (int u = tid; u < 32 * 64; u += 256) {
        int r = u >> 6, c4 = u & 63;
        *reinterpret_cast<float4*>(outq + (size_t)(blockIdx.x * 32 + r) * DDIM + c4 * 4) =
            *reinterpret_cast<const float4*>(w + (size_t)winners[r] * DDIM + c4 * 4);
    }
}

extern "C" void kernel_launch(void* const* d_in, const int* in_sizes, int n_in,
                              void* d_out, int out_size, void* d_ws, size_t ws_size,
                              hipStream_t stream) {
    const float* x = (const float*)d_in[0];
    const float* w = (const float*)d_in[1];
    const int N = in_sizes[0] / DDIM;   // 32768
    const int K = in_sizes[1] / DDIM;   // 8192
    float* outq = (float*)d_out;
    float* outi = outq + (size_t)N * DDIM;

    unsigned char* wb8 = (unsigned char*)d_ws;                // K*256 = 2 MB
    float* wn = (float*)(wb8 + (size_t)K * DDIM);             // K floats
    unsigned* cand = (unsigned*)(wn + K);                     // N*8 u32 = 1 MB

    hipLaunchKernelGGL(vq_prep_w, dim3(K / 32), dim3(256), 0, stream, w, wn, wb8);
    hipLaunchKernelGGL(vq_score, dim3(N / 64), dim3(256), 0, stream, x, wb8, cand);
    hipLaunchKernelGGL(vq_rescore_write, dim3(N / 32), dim3(256), 0, stream,
                       x, w, wn, cand, outq, outi);
}

// Round 5
// 249.852 us; speedup vs baseline: 1.0927x; 1.0927x over previous
//
#include <hip/hip_runtime.h>
#include <cfloat>

// VectorQuantizer: N=32768 rows, K=8192 codes, D=256, fp32.
// R2/R3 (absmax 0): reference = numpy fp32; d_k = fl32(fl32(x2+wn_k)-fl32(2*m_k)),
// m_k = single fp32 FMA chain d-ascending; first-occurrence argmin. Exact top-8
// rescore of approximate-scorer candidates reproduces it bit-for-bit.
// R6 (125.3us score, absmax 0): 2 blocks/CU, in-kernel A fp8, top-2/slot keys,
//   2x32KB dbuf + per-kt __syncthreads (full vmcnt drain). 0 bank conflicts.
// R7 (140us): spill (4 acc sets) + 4-way bank conflicts (128B stride). Reverted.
// R9 (FAILED absmax 8080): counted-vmcnt pipeline + asm v_and_or/v_med3 SEL,
//   bundled. Can't attribute the failure -> R10 bisects.
// R10: pipeline ONLY; selection reverted to R6's exact C code.
//   Key fact: each wave stages AND reads only its own 8KB LDS quarter
//   (stage slots wave*8..+7 = cols wave*32..+31 = its read cols) -> the K-loop
//   has NO cross-wave data flow. So: barrier-FREE per-wave pipeline:
//     prologue: stage(0)->buf0                       [ 8 outstanding]
//     iter kt<63: stage(kt+1 -> buf (kt+1)&1)        [16 outstanding]
//                 s_waitcnt vmcnt(8)  == tile kt landed, kt+1 in flight
//                 sched_barrier(0) (rule-18 pin) -> MFMA(buf kt&1) -> SEL(kt)
//     peeled kt=63: vmcnt(0) -> MFMA(buf1) -> SEL(63)
//   WAR safe within-wave: a buffer's ds_reads retire (lgkmcnt) before its
//   MFMAs, which precede the next stage into it in program order.
//   __syncthreads only before merge (first cross-wave flow).
//   setprio(1) around MFMA clusters (free-running waves regime).
// R11 (this round): R10 died to an infra flake ("container failed twice", no
//   counters) -- same precedent as R7->R8 where identical resubmit ran fine.
//   Re-audited hang paths: vmcnt ledger always drains (8 / 16->8 / 0), no
//   in-loop barriers, uniform __syncthreads, bounds exact. Resubmitted as-is.
// prep_w / rescore untouched (bit-exact verified).

#define DDIM 256

typedef int   i32x8  __attribute__((ext_vector_type(8)));
typedef float f32x16 __attribute__((ext_vector_type(16)));

// ---------- W prep: numpy-exact ||w||^2 + negated scaled fp8 ----------
__global__ __launch_bounds__(256) void vq_prep_w(
    const float* __restrict__ w, float* __restrict__ wn,
    unsigned char* __restrict__ wb8) {
    __shared__ float rows[32 * 260];
    const int tid = threadIdx.x;
    const int r0 = blockIdx.x * 32;

    for (int idx = tid; idx < 32 * 64; idx += 256) {
        int r = idx >> 6, c4 = idx & 63;
        *(float4*)&rows[r * 260 + c4 * 4] =
            *(const float4*)(w + (size_t)(r0 + r) * DDIM + c4 * 4);
    }
    __syncthreads();
    {
        // numpy pairwise_sum(fl(a*a),256): two 128-halves, each 8 stride-8
        // chains, ((r0+r1)+(r2+r3))+((r4+r5)+(r6+r7)); shfl-xor == nesting.
        const int row = (tid >> 6) * 8 + ((tid & 63) >> 3), j = tid & 7;
        const float* a = &rows[row * 260];
        float half[2];
#pragma unroll
        for (int h = 0; h < 2; ++h) {
            const float* b = a + h * 128 + j;
            float r = __fmul_rn(b[0], b[0]);
#pragma unroll
            for (int t = 1; t < 16; ++t)
                r = __fadd_rn(r, __fmul_rn(b[8 * t], b[8 * t]));
            float p = __fadd_rn(r, __shfl_xor(r, 1, 64));
            p = __fadd_rn(p, __shfl_xor(p, 2, 64));
            p = __fadd_rn(p, __shfl_xor(p, 4, 64));
            half[h] = p;
        }
        if (j == 0) wn[r0 + row] = __fadd_rn(half[0], half[1]);
    }
    // fp8 e4m3 emission, scaled by -2^13 (pow2 cancels in argmin; negation
    // folds the "-2m" sign so acc = C - m_s with C=128 init)
    for (int idx = tid; idx < 32 * 16; idx += 256) {
        int r = idx >> 4, s = idx & 15;
        const float* p = &rows[r * 260 + s * 16];
        unsigned q[4];
#pragma unroll
        for (int m = 0; m < 4; ++m) {
            unsigned v = (unsigned)__builtin_amdgcn_cvt_pk_fp8_f32(
                p[m * 4 + 0] * -8192.f, p[m * 4 + 1] * -8192.f, 0, false);
            v = (unsigned)__builtin_amdgcn_cvt_pk_fp8_f32(
                p[m * 4 + 2] * -8192.f, p[m * 4 + 3] * -8192.f, (int)v, true);
            q[m] = v;
        }
        *(uint4*)(wb8 + (size_t)(r0 + r) * DDIM + s * 16) =
            make_uint4(q[0], q[1], q[2], q[3]);
    }
}

// ---------- MX-fp8 scorer: 64 rows x 8192 cols per block, 2 blocks/CU ----------
// 256 thr = 4 waves (wave = 32-col group); wave tile 64r x 32c = 2 MFMA
// 32x32x64 tiles. A resident in VGPRs (converted in-kernel). W 128c x 256k
// = 32 KB tiles, 2 buffers, global_load_lds (16B), XOR-swizzled granules
// (R6 map: granule g of col at slot g^(col&15), 256B column stride --
// measured ZERO bank conflicts).
// C/D (32x32): col=lane&31, row=(reg&3)+8*(reg>>2)+4*(lane>>5)  [m74/m101].

#define VWAIT(n) do { \
    asm volatile("s_waitcnt vmcnt(" #n ")" ::: "memory"); \
    __builtin_amdgcn_sched_barrier(0); \
  } while (0)

#define INIT128(C) { _Pragma("unroll") for (int r_ = 0; r_ < 16; ++r_) (C)[r_] = 128.0f; }

// selection: R6 VERBATIM. acc = 128 - m_s > 0, uint-monotone; top-2 per slot.
#define SEL16(P, rt, pkt) { \
    const unsigned colv_ = (unsigned)((pkt) * 128 + bcol); \
    _Pragma("unroll") for (int r_ = 0; r_ < 16; ++r_) { \
        unsigned key_ = (__float_as_uint((P)[r_]) & 0xFFFFE000u) | colv_; \
        unsigned a0_ = s0[rt][r_]; \
        unsigned mx_ = key_ > a0_ ? key_ : a0_; \
        s1[rt][r_] = mx_ < s1[rt][r_] ? mx_ : s1[rt][r_]; \
        s0[rt][r_] = key_ < a0_ ? key_ : a0_; \
    } }

__global__ __launch_bounds__(256, 2) void vq_score(
    const float* __restrict__ x, const unsigned char* __restrict__ wb8,
    unsigned* __restrict__ cand) {
    __shared__ __align__(16) unsigned char Ws[2][32768];
    const int tid = threadIdx.x;
    const int wave = tid >> 6, lane = tid & 63;
    const int h = lane >> 5, c32 = lane & 31;
    const int rowBase = blockIdx.x * 64;
    const unsigned char* wsb = (const unsigned char*)&Ws[0][0];

    // A fragments: 64 rows x 256 k fp8, converted from fp32 global (one-time)
    i32x8 af[2][4];
#pragma unroll
    for (int rt = 0; rt < 2; ++rt) {
        const float* xr = x + (size_t)(rowBase + rt * 32 + c32) * DDIM;
#pragma unroll
        for (int ks = 0; ks < 4; ++ks) {
            const float4* p = (const float4*)(xr + ks * 64 + h * 32);
            union { int d[8]; i32x8 v; } u;
#pragma unroll
            for (int m = 0; m < 8; ++m) {
                float4 f = p[m];
                unsigned v = (unsigned)__builtin_amdgcn_cvt_pk_fp8_f32(
                    f.x, f.y, 0, false);
                v = (unsigned)__builtin_amdgcn_cvt_pk_fp8_f32(
                    f.z, f.w, (int)v, true);
                u.d[m] = (int)v;
            }
            af[rt][ks] = u.v;
        }
    }
    // clean vmcnt baseline for the counted pipeline (drains the A loads)
    asm volatile("s_waitcnt vmcnt(0)" ::: "memory");

    // staging map (R6 VERBATIM): 4 waves x 8 instr x 64 lanes = 2048 granules
    // (16B) = 32 KB per tile. slot covers 4 cols; granule XOR-placed by col&15.
    // Wave w stages slots w*8..w*8+7 = LDS bytes [w*8192,(w+1)*8192) = its own
    // read region (bcol in [w*32,(w+1)*32)) -> NO cross-wave flow in K-loop.
    unsigned sOfs[8], ldsOfs[8];
#pragma unroll
    for (int i = 0; i < 8; ++i) {
        int slot = wave * 8 + i;                  // 0..31
        int col  = slot * 4 + (lane >> 4);        // 0..127
        int gsrc = (lane & 15) ^ (col & 15);      // XOR bank spread
        sOfs[i]   = (unsigned)(col * 256 + gsrc * 16);
        ldsOfs[i] = (unsigned)(slot * 1024);      // + lane*16 implicit
    }
    auto stage = [&](int kt, unsigned tgl) {
        const unsigned char* g = wb8 + (size_t)kt * 32768;
#pragma unroll
        for (int i = 0; i < 8; ++i)
            __builtin_amdgcn_global_load_lds(
                (const __attribute__((address_space(1))) unsigned int*)(g + sOfs[i]),
                (__attribute__((address_space(3))) unsigned int*)(
                    &Ws[0][0] + tgl + ldsOfs[i]),
                16, 0, 0);
    };

    // B-fragment read offsets (R6 VERBATIM): granule gb of col bcol sits at
    // bcol*256 + (gb^(bcol&15))*16 within a 32KB buffer.
    const int bcol = wave * 32 + c32, cs = bcol & 15;
    int bofs[4][2];
#pragma unroll
    for (int ks = 0; ks < 4; ++ks) {
        int gb = ks * 4 + h * 2;
        bofs[ks][0] = bcol * 256 + ((gb)     ^ cs) * 16;
        bofs[ks][1] = bcol * 256 + ((gb + 1) ^ cs) * 16;
    }

    unsigned s0[2][16], s1[2][16];
#pragma unroll
    for (int a = 0; a < 2; ++a)
#pragma unroll
        for (int r = 0; r < 16; ++r) { s0[a][r] = 0xFFFFFFFFu; s1[a][r] = 0xFFFFFFFFu; }

    f32x16 acc0, acc1;

    // Per-wave pipeline ledger (8 loads/wave/tile):
    //   stage(0)->buf0 [8]; iter kt: stage(kt+1)->other buf [16];
    //   vmcnt(8) -> tile kt landed (oldest 8), tile kt+1 in flight;
    //   iter 62 stages 63; peeled 63: no stage, vmcnt(0).
    //   WAR: buffer's ds_reads retire before its MFMAs (compiler lgkmcnt),
    //   which precede the next stage into that buffer in program order.
    stage(0, 0);

    for (int kt = 0; kt < 63; ++kt) {
        const unsigned tgl = (unsigned)(kt & 1) << 15;
        stage(kt + 1, tgl ^ 32768u);
        INIT128(acc0); INIT128(acc1);
        VWAIT(8);
        __builtin_amdgcn_s_setprio(1);
#pragma unroll
        for (int ks = 0; ks < 4; ++ks) {
            union { uint4 q[2]; i32x8 v; } b_;
            b_.q[0] = *(const uint4*)(wsb + tgl + bofs[ks][0]);
            b_.q[1] = *(const uint4*)(wsb + tgl + bofs[ks][1]);
            acc0 = __builtin_amdgcn_mfma_scale_f32_32x32x64_f8f6f4(
                af[0][ks], b_.v, acc0, 0, 0, 0, 0x7F7F7F7F, 0, 0x7F7F7F7F);
            acc1 = __builtin_amdgcn_mfma_scale_f32_32x32x64_f8f6f4(
                af[1][ks], b_.v, acc1, 0, 0, 0, 0x7F7F7F7F, 0, 0x7F7F7F7F);
        }
        __builtin_amdgcn_s_setprio(0);
        SEL16(acc0, 0, kt);
        SEL16(acc1, 1, kt);
    }
    // kt = 63 (peeled tail): drain and compute buf1
    {
        INIT128(acc0); INIT128(acc1);
        VWAIT(0);
        __builtin_amdgcn_s_setprio(1);
#pragma unroll
        for (int ks = 0; ks < 4; ++ks) {
            union { uint4 q[2]; i32x8 v; } b_;
            b_.q[0] = *(const uint4*)(wsb + 32768 + bofs[ks][0]);
            b_.q[1] = *(const uint4*)(wsb + 32768 + bofs[ks][1]);
            acc0 = __builtin_amdgcn_mfma_scale_f32_32x32x64_f8f6f4(
                af[0][ks], b_.v, acc0, 0, 0, 0, 0x7F7F7F7F, 0, 0x7F7F7F7F);
            acc1 = __builtin_amdgcn_mfma_scale_f32_32x32x64_f8f6f4(
                af[1][ks], b_.v, acc1, 0, 0, 0, 0x7F7F7F7F, 0, 0x7F7F7F7F);
        }
        __builtin_amdgcn_s_setprio(0);
        SEL16(acc0, 0, 63);
        SEL16(acc1, 1, 63);
    }

    // merge: 64 rows x 256 keys = 64 KB (reuse Ws) -- first cross-wave flow
    __syncthreads();
    unsigned* ms = (unsigned*)Ws;
#pragma unroll
    for (int rt = 0; rt < 2; ++rt)
#pragma unroll
        for (int r = 0; r < 16; ++r) {
            int rloc = rt * 32 + (r & 3) + 8 * (r >> 2) + 4 * h;
            *(uint2*)&ms[rloc * 256 + bcol * 2] = make_uint2(s0[rt][r], s1[rt][r]);
        }
    __syncthreads();
    if (tid < 64) {
        const uint4* rowk = (const uint4*)(ms + tid * 256);
        unsigned best[8];
#pragma unroll
        for (int i = 0; i < 8; ++i) best[i] = 0xFFFFFFFFu;
        for (int i = 0; i < 64; ++i) {
            uint4 qv = rowk[(i + tid) & 63];   // rotated: bank spread
            unsigned kk[4] = {qv.x, qv.y, qv.z, qv.w};
#pragma unroll
            for (int e = 0; e < 4; ++e) {
                unsigned key = kk[e];
                if (key < best[7]) {
                    best[7] = key;
#pragma unroll
                    for (int j = 7; j > 0; --j)
                        if (best[j] < best[j - 1]) {
                            unsigned t = best[j]; best[j] = best[j - 1]; best[j - 1] = t;
                        }
                }
            }
        }
        unsigned* out = cand + (size_t)(rowBase + tid) * 8;
#pragma unroll
        for (int i = 0; i < 8; ++i) out[i] = best[i];
    }
}

// ---------- exact rescore (fp32 chain, R3-verified) + inline numpy x2 ----------
__global__ __launch_bounds__(256) void vq_rescore_write(
    const float* __restrict__ x, const float* __restrict__ w,
    const float* __restrict__ wn, const unsigned* __restrict__ cand,
    float* __restrict__ outq, float* __restrict__ outi) {
    __shared__ int winners[32];
    const int tid = threadIdx.x;
    const int lr = tid >> 3, cc = tid & 7;
    const int row = blockIdx.x * 32 + lr;

    int k = (int)(cand[(size_t)row * 8 + cc] & 0x1FFFu);
    const float* xr = x + (size_t)row * DDIM;
    const float* wr = w + (size_t)k * DDIM;
    // dot: single fp32 fmaf chain d-ascending (BLAS-exact, R2/R3-verified)
    // x2: numpy pairwise (two halves, 8 stride-8 chains, exact nesting)
    float dot = 0.f;
    float half[2];
#pragma unroll
    for (int hh = 0; hh < 2; ++hh) {
        float r[8];
#pragma unroll
        for (int t = 0; t < 16; ++t) {
            const int d = hh * 128 + t * 8;
            float4 xa = *(const float4*)(xr + d);
            float4 xb = *(const float4*)(xr + d + 4);
            float4 wa = *(const float4*)(wr + d);
            float4 wb = *(const float4*)(wr + d + 4);
            dot = __fmaf_rn(xa.x, wa.x, dot); dot = __fmaf_rn(xa.y, wa.y, dot);
            dot = __fmaf_rn(xa.z, wa.z, dot); dot = __fmaf_rn(xa.w, wa.w, dot);
            dot = __fmaf_rn(xb.x, wb.x, dot); dot = __fmaf_rn(xb.y, wb.y, dot);
            dot = __fmaf_rn(xb.z, wb.z, dot); dot = __fmaf_rn(xb.w, wb.w, dot);
            if (t == 0) {
                r[0] = __fmul_rn(xa.x, xa.x); r[1] = __fmul_rn(xa.y, xa.y);
                r[2] = __fmul_rn(xa.z, xa.z); r[3] = __fmul_rn(xa.w, xa.w);
                r[4] = __fmul_rn(xb.x, xb.x); r[5] = __fmul_rn(xb.y, xb.y);
                r[6] = __fmul_rn(xb.z, xb.z); r[7] = __fmul_rn(xb.w, xb.w);
            } else {
                r[0] = __fadd_rn(r[0], __fmul_rn(xa.x, xa.x));
                r[1] = __fadd_rn(r[1], __fmul_rn(xa.y, xa.y));
                r[2] = __fadd_rn(r[2], __fmul_rn(xa.z, xa.z));
                r[3] = __fadd_rn(r[3], __fmul_rn(xa.w, xa.w));
                r[4] = __fadd_rn(r[4], __fmul_rn(xb.x, xb.x));
                r[5] = __fadd_rn(r[5], __fmul_rn(xb.y, xb.y));
                r[6] = __fadd_rn(r[6], __fmul_rn(xb.w == xb.w ? xb.z : xb.z, xb.z));
                r[7] = __fadd_rn(r[7], __fmul_rn(xb.w, xb.w));
            }
        }
        half[hh] = __fadd_rn(__fadd_rn(__fadd_rn(r[0], r[1]), __fadd_rn(r[2], r[3])),
                             __fadd_rn(__fadd_rn(r[4], r[5]), __fadd_rn(r[6], r[7])));
    }
    float x2v = __fadd_rn(half[0], half[1]);
    float dv = __fsub_rn(__fadd_rn(x2v, wn[k]), __fmul_rn(2.0f, dot));
    // lexicographic (dv,k) min across 8 candidate lanes (first-occurrence)
#pragma unroll
    for (int m = 1; m < 8; m <<= 1) {
        float od = __shfl_xor(dv, m, 64);
        int   ok = __shfl_xor(k,  m, 64);
        if (od < dv || (od == dv && ok < k)) { dv = od; k = ok; }
    }
    if (cc == 0) winners[lr] = k;
    __syncthreads();
    if (tid < 32) outi[blockIdx.x * 32 + tid] = (float)winners[tid];
    for (int u = tid; u < 32 * 64; u += 256) {
        int r = u >> 6, c4 = u & 63;
        *reinterpret_cast<float4*>(outq + (size_t)(blockIdx.x * 32 + r) * DDIM + c4 * 4) =
            *reinterpret_cast<const float4*>(w + (size_t)winners[r] * DDIM + c4 * 4);
    }
}

extern "C" void kernel_launch(void* const* d_in, const int* in_sizes, int n_in,
                              void* d_out, int out_size, void* d_ws, size_t ws_size,
                              hipStream_t stream) {
    const float* x = (const float*)d_in[0];
    const float* w = (const float*)d_in[1];
    const int N = in_sizes[0] / DDIM;   // 32768
    const int K = in_sizes[1] / DDIM;   // 8192
    float* outq = (float*)d_out;
    float* outi = outq + (size_t)N * DDIM;

    unsigned char* wb8 = (unsigned char*)d_ws;                // K*256 = 2 MB
    float* wn = (float*)(wb8 + (size_t)K * DDIM);             // K floats
    unsigned* cand = (unsigned*)(wn + K);                     // N*8 u32 = 1 MB

    hipLaunchKernelGGL(vq_prep_w, dim3(K / 32), dim3(256), 0, stream, w, wn, wb8);
    hipLaunchKernelGGL(vq_score, dim3(N / 64), dim3(256), 0, stream, x, wb8, cand);
    hipLaunchKernelGGL(vq_rescore_write, dim3(N / 32), dim3(256), 0, stream,
                       x, w, wn, cand, outq, outi);
}